// Round 1
// baseline (45.654 us; speedup 1.0000x reference)
//
#include <hip/hip_runtime.h>

// MonotonicityLoss: loss = mean over pairs {same group, galloyl_i > galloyl_j}
// of relu(pred_i - pred_j + MARGIN)^2.
// B=8192 -> 67M ordered pairs, brute force 2D-tiled, VALU-bound (few us).

constexpr int   BLOCK  = 256;   // i-tile size = block size
constexpr int   JS     = 256;   // j-slice size staged in LDS
constexpr float MARGIN = 0.1f;

__global__ __launch_bounds__(BLOCK)
void mono_pairs_kernel(const float* __restrict__ pred,
                       const int*   __restrict__ gall,
                       const int*   __restrict__ grp,
                       int n, int n_itiles,
                       double* __restrict__ d_total,
                       unsigned long long* __restrict__ d_count)
{
    __shared__ float              s_pred[JS];
    __shared__ int                s_meta[JS];
    __shared__ double             s_wsum[BLOCK / 64];
    __shared__ unsigned long long s_wcnt[BLOCK / 64];

    const int tid    = threadIdx.x;
    const int itile  = blockIdx.x % n_itiles;
    const int jslice = blockIdx.x / n_itiles;

    // ---- stage this block's j-slice into LDS ----
    {
        const int j = jslice * JS + tid;
        if (j < n) {
            s_pred[tid] = pred[j];
            s_meta[tid] = (grp[j] << 8) | gall[j];   // 12-bit packed meta
        } else {
            s_pred[tid] = 0.0f;
            s_meta[tid] = 0x40000000;   // sentinel: mi > mj never true
        }
    }
    __syncthreads();

    // ---- per-thread i ----
    const int i  = itile * BLOCK + tid;
    float pim = 0.0f;
    int   mi  = (int)0x80000000;        // sentinel: mi > mj never true
    if (i < n) {
        pim = pred[i] + MARGIN;         // fold margin into pred_i
        mi  = (grp[i] << 8) | gall[i];
    }

    float vsum = 0.0f;
    int   vcnt = 0;
    #pragma unroll 8
    for (int t = 0; t < JS; ++t) {
        const float pj = s_pred[t];     // same addr across wave -> LDS broadcast
        const int   mj = s_meta[t];
        const bool  m  = (((mi ^ mj) >> 8) == 0) & (mi > mj);
        const float d  = pim - pj;      // pred_i - pred_j + margin
        const float r  = (m && d > 0.0f) ? d : 0.0f;
        vsum = fmaf(r, r, vsum);
        vcnt += (int)m;
    }

    // ---- wave (64-lane) shuffle reduction ----
    double             wsum = (double)vsum;
    unsigned long long wcnt = (unsigned long long)vcnt;
    for (int off = 32; off > 0; off >>= 1) {
        wsum += __shfl_down(wsum, off);
        wcnt += __shfl_down(wcnt, off);
    }
    const int wave = tid >> 6;
    if ((tid & 63) == 0) { s_wsum[wave] = wsum; s_wcnt[wave] = wcnt; }
    __syncthreads();

    // ---- block reduction + one atomic per block ----
    if (tid == 0) {
        double             bs = 0.0;
        unsigned long long bc = 0ull;
        #pragma unroll
        for (int w = 0; w < BLOCK / 64; ++w) { bs += s_wsum[w]; bc += s_wcnt[w]; }
        atomicAdd(d_total, bs);
        atomicAdd(d_count, bc);
    }
}

__global__ void mono_finalize_kernel(const double* __restrict__ d_total,
                                     const unsigned long long* __restrict__ d_count,
                                     float* __restrict__ out)
{
    const double             t = *d_total;
    const unsigned long long c = *d_count;
    out[0] = (c > 0ull) ? (float)(t / (double)c) : 0.0f;
}

extern "C" void kernel_launch(void* const* d_in, const int* in_sizes, int n_in,
                              void* d_out, int out_size, void* d_ws, size_t ws_size,
                              hipStream_t stream)
{
    const float* pred = (const float*)d_in[0];
    const int*   gall = (const int*)d_in[1];
    const int*   grp  = (const int*)d_in[2];
    const int    n    = in_sizes[0];

    double*             d_total = (double*)d_ws;
    unsigned long long* d_count = (unsigned long long*)((char*)d_ws + sizeof(double));

    hipMemsetAsync(d_ws, 0, 2 * sizeof(unsigned long long), stream);

    const int n_itiles  = (n + BLOCK - 1) / BLOCK;   // 32 for n=8192
    const int n_jslices = (n + JS - 1) / JS;         // 32
    dim3 grid(n_itiles * n_jslices);                 // 1024 blocks -> 4/CU

    mono_pairs_kernel<<<grid, BLOCK, 0, stream>>>(pred, gall, grp, n, n_itiles,
                                                  d_total, d_count);
    mono_finalize_kernel<<<1, 1, 0, stream>>>(d_total, d_count, (float*)d_out);
}

// Round 2
// 22.791 us; speedup vs baseline: 2.0031x; 2.0031x over previous
//
#include <hip/hip_runtime.h>

// MonotonicityLoss: loss = mean over pairs {same group, galloyl_i > galloyl_j}
// of relu(pred_i - pred_j + MARGIN)^2.
// B=8192 -> 67M ordered pairs, brute force 2D-tiled, VALU-bound.
// R1 lesson: a 16-byte hipMemsetAsync node cost ~39us/replay. Replaced
// atomics-into-zeroed-accumulator with per-block partials (overwritten every
// call, no init needed) + a reduction kernel.

constexpr int   BLOCK  = 256;   // i-tile size = block size
constexpr int   JS     = 256;   // j-slice size staged in LDS
constexpr float MARGIN = 0.1f;

__global__ __launch_bounds__(BLOCK)
void mono_pairs_kernel(const float* __restrict__ pred,
                       const int*   __restrict__ gall,
                       const int*   __restrict__ grp,
                       int n, int n_itiles,
                       double* __restrict__ part_sum,
                       unsigned long long* __restrict__ part_cnt)
{
    __shared__ float              s_pred[JS];
    __shared__ int                s_meta[JS];
    __shared__ double             s_wsum[BLOCK / 64];
    __shared__ unsigned long long s_wcnt[BLOCK / 64];

    const int tid    = threadIdx.x;
    const int itile  = blockIdx.x % n_itiles;
    const int jslice = blockIdx.x / n_itiles;

    // ---- stage this block's j-slice into LDS ----
    {
        const int j = jslice * JS + tid;
        if (j < n) {
            s_pred[tid] = pred[j];
            s_meta[tid] = (grp[j] << 8) | gall[j];   // 12-bit packed meta
        } else {
            s_pred[tid] = 0.0f;
            s_meta[tid] = 0x40000000;   // sentinel: mi > mj never true
        }
    }
    __syncthreads();

    // ---- per-thread i ----
    const int i  = itile * BLOCK + tid;
    float pim = 0.0f;
    int   mi  = (int)0x80000000;        // sentinel: mi > mj never true
    if (i < n) {
        pim = pred[i] + MARGIN;         // fold margin into pred_i
        mi  = (grp[i] << 8) | gall[i];
    }

    float vsum = 0.0f;
    int   vcnt = 0;
    #pragma unroll 8
    for (int t = 0; t < JS; ++t) {
        const float pj = s_pred[t];     // same addr across wave -> LDS broadcast
        const int   mj = s_meta[t];
        const bool  m  = (((mi ^ mj) >> 8) == 0) & (mi > mj);
        const float d  = pim - pj;      // pred_i - pred_j + margin
        const float r  = (m && d > 0.0f) ? d : 0.0f;
        vsum = fmaf(r, r, vsum);
        vcnt += (int)m;
    }

    // ---- wave (64-lane) shuffle reduction ----
    double             wsum = (double)vsum;
    unsigned long long wcnt = (unsigned long long)vcnt;
    for (int off = 32; off > 0; off >>= 1) {
        wsum += __shfl_down(wsum, off);
        wcnt += __shfl_down(wcnt, off);
    }
    const int wave = tid >> 6;
    if ((tid & 63) == 0) { s_wsum[wave] = wsum; s_wcnt[wave] = wcnt; }
    __syncthreads();

    // ---- block reduction -> this block's partial slot (overwrite, no init) ----
    if (tid == 0) {
        double             bs = 0.0;
        unsigned long long bc = 0ull;
        #pragma unroll
        for (int w = 0; w < BLOCK / 64; ++w) { bs += s_wsum[w]; bc += s_wcnt[w]; }
        part_sum[blockIdx.x] = bs;
        part_cnt[blockIdx.x] = bc;
    }
}

__global__ __launch_bounds__(256)
void mono_finalize_kernel(const double* __restrict__ part_sum,
                          const unsigned long long* __restrict__ part_cnt,
                          int n_parts,
                          float* __restrict__ out)
{
    __shared__ double             s_wsum[4];
    __shared__ unsigned long long s_wcnt[4];

    const int tid = threadIdx.x;
    double             ts = 0.0;
    unsigned long long tc = 0ull;
    for (int p = tid; p < n_parts; p += 256) {
        ts += part_sum[p];
        tc += part_cnt[p];
    }
    for (int off = 32; off > 0; off >>= 1) {
        ts += __shfl_down(ts, off);
        tc += __shfl_down(tc, off);
    }
    const int wave = tid >> 6;
    if ((tid & 63) == 0) { s_wsum[wave] = ts; s_wcnt[wave] = tc; }
    __syncthreads();
    if (tid == 0) {
        double             bs = 0.0;
        unsigned long long bc = 0ull;
        #pragma unroll
        for (int w = 0; w < 4; ++w) { bs += s_wsum[w]; bc += s_wcnt[w]; }
        out[0] = (bc > 0ull) ? (float)(bs / (double)bc) : 0.0f;
    }
}

extern "C" void kernel_launch(void* const* d_in, const int* in_sizes, int n_in,
                              void* d_out, int out_size, void* d_ws, size_t ws_size,
                              hipStream_t stream)
{
    const float* pred = (const float*)d_in[0];
    const int*   gall = (const int*)d_in[1];
    const int*   grp  = (const int*)d_in[2];
    const int    n    = in_sizes[0];

    const int n_itiles  = (n + BLOCK - 1) / BLOCK;   // 32 for n=8192
    const int n_jslices = (n + JS - 1) / JS;         // 32
    const int n_blocks  = n_itiles * n_jslices;      // 1024 -> 4 blocks/CU

    double*             part_sum = (double*)d_ws;
    unsigned long long* part_cnt = (unsigned long long*)((char*)d_ws
                                   + (size_t)n_blocks * sizeof(double));

    mono_pairs_kernel<<<n_blocks, BLOCK, 0, stream>>>(pred, gall, grp, n, n_itiles,
                                                      part_sum, part_cnt);
    mono_finalize_kernel<<<1, 256, 0, stream>>>(part_sum, part_cnt, n_blocks,
                                                (float*)d_out);
}